// Round 2
// 230.600 us; speedup vs baseline: 1.0298x; 1.0298x over previous
//
#include <hip/hip_runtime.h>

#define N_NODES 50000
#define BATCH   512
#define DIM     32
#define LOG2E 1.4426950408889634f
#define LN2   0.6931471805599453f
// ln(1+t) ~= t*(A1 + A2*t + A3*t^2) on [0,1], max abs err ~2e-3
#define A1C 0.996829f
#define A2C (-0.441666f)
#define A3C 0.139730f

typedef float vfloat4 __attribute__((ext_vector_type(4)));

// Kernel A: blocks 0..195 = per-node projections; blocks 196..197 = per-batch scalars
__global__ void prep_kernel(const float* __restrict__ emb,
                            const int*   __restrict__ assoc,
                            const int*   __restrict__ src,
                            const int*   __restrict__ pdst,
                            const float* __restrict__ last_update,
                            const float* __restrict__ cur_time,
                            const int*   __restrict__ et,
                            const float* __restrict__ W,
                            const float* __restrict__ bias,
                            const float* __restrict__ psi,
                            const float* __restrict__ alpha,
                            const float* __restrict__ w_t,
                            float* __restrict__ nv0, float* __restrict__ nv1,
                            float* __restrict__ nu0, float* __restrict__ nu1,
                            float* __restrict__ pb) {
    if (blockIdx.x < 196) {
        int n = blockIdx.x * 256 + threadIdx.x;
        if (n >= N_NODES) return;
        const float4* e4 = (const float4*)(emb + (size_t)n * DIM);
        float u0 = 0.f, u1 = 0.f, v0 = 0.f, v1 = 0.f;
#pragma unroll
        for (int q = 0; q < 8; ++q) {
            float4 v = e4[q];
            int d = q * 4;
            u0 += v.x * W[d]      + v.y * W[d + 1]      + v.z * W[d + 2]      + v.w * W[d + 3];
            v0 += v.x * W[32 + d] + v.y * W[32 + d + 1] + v.z * W[32 + d + 2] + v.w * W[32 + d + 3];
            u1 += v.x * W[64 + d] + v.y * W[64 + d + 1] + v.z * W[64 + d + 2] + v.w * W[64 + d + 3];
            v1 += v.x * W[96 + d] + v.y * W[96 + d + 1] + v.z * W[96 + d + 2] + v.w * W[96 + d + 3];
        }
        nu0[n] = u0; nu1[n] = u1; nv0[n] = v0; nv1[n] = v1;
    } else {
        int b = (blockIdx.x - 196) * 256 + threadIdx.x;
        if (b >= BATCH) return;
        int e  = (et[b] > 0) ? 1 : 0;
        int is = assoc[src[b]];
        int id = assoc[pdst[b]];
        const float4* Wu = (const float4*)(W + e * 64);
        const float4* Wv = (const float4*)(W + e * 64 + 32);
        const float4* zs = (const float4*)(emb + (size_t)is * DIM);
        const float4* zd = (const float4*)(emb + (size_t)id * DIM);
        float su = 0.f, dv = 0.f;
#pragma unroll
        for (int q = 0; q < 8; ++q) {
            float4 a = zs[q], wa = Wu[q];
            float4 c = zd[q], wc = Wv[q];
            su += a.x * wa.x + a.y * wa.y + a.z * wa.z + a.w * wa.w;
            dv += c.x * wc.x + c.y * wc.y + c.z * wc.z + c.w * wc.w;
        }
        float ct  = cur_time[b];
        float tds = (ct - last_update[is]) * 0.01f;
        float tdd = (ct - last_update[id]) * 0.01f;
        float al = alpha[e], wt = w_t[e], bb = bias[e], ps = psi[e];
        float ip  = 1.0f / (ps + 1e-7f);
        float ipl = ip * LOG2E;
        float bs = su + bb + al * __expf(-wt * tds);
        float bd = dv + bb + al * __expf(-wt * tdd);
        float* p = pb + (size_t)b * 16;
        p[0]  = bs * ipl;        // src base, log2 domain
        p[1]  = bd * ipl;        // dst base, log2 domain
        p[2]  = ipl;
        p[3]  = ps * LN2;        // C1
        p[4]  = ps * A1C;
        p[5]  = ps * A2C;
        p[6]  = ps * A3C;
        p[7]  = (float)e;
        p[8]  = su + dv + bb;    // bint for rtp
        p[9]  = al;
        p[10] = wt;
        p[11] = ps;
        p[12] = ip;
        p[13] = 0.f; p[14] = 0.f; p[15] = 0.f;
    }
}

// Kernel B: grid (26, 512). x<25: lambda maps, 8 floats/thread/output, plain (temporal)
// float4 stores so L2 write-combines into full lines. x==25: rtp block scan.
__global__ void __launch_bounds__(256) main_kernel(
        const float* __restrict__ nv0, const float* __restrict__ nv1,
        const float* __restrict__ nu0, const float* __restrict__ nu1,
        const float* __restrict__ pb,
        float* __restrict__ out) {
    __shared__ float wsum[4];
    __shared__ float bred[4];
    int b = blockIdx.y;
    const float* p = pb + (size_t)b * 16;

    if (blockIdx.x < 25) {
        int n8 = blockIdx.x * 256 + threadIdx.x;   // 8-float chunk id
        if (n8 >= N_NODES / 8) return;
        const float4* p4 = (const float4*)p;
        float4 pa = p4[0];   // bsl, bdl, ipl, C1
        float4 pc = p4[1];   // A1p, A2p, A3p, e
        float bsl = pa.x, bdl = pa.y, ipl = pa.z, C1 = pa.w;
        float A1p = pc.x, A2p = pc.y, A3p = pc.z;
        int e = (pc.w != 0.f);
        const float4* nvp = (const float4*)(e ? nv1 : nv0) + (size_t)n8 * 2;
        const float4* nup = (const float4*)(e ? nu1 : nu0) + (size_t)n8 * 2;
        float4 nva = nvp[0], nvb = nvp[1];
        float4 nua = nup[0], nub = nup[1];
        auto f = [&](float nvx, float base) {
            float xl = fmaf(nvx, ipl, base);                    // g/psi in log2 units
            float t  = __builtin_amdgcn_exp2f(-fabsf(xl));      // e^{-|x|}
            float pp = fmaf(t, A3p, A2p);
            pp = fmaf(t, pp, A1p);                              // psi*(a1+a2 t+a3 t^2)
            float m = fmaxf(xl, 0.f);
            return fmaf(pp, t, m * C1);                         // psi*ln(1+t) + psi*ln2*max(xl,0)
        };
        float4 osa, osb, oda, odb;
        osa.x = f(nva.x, bsl); osa.y = f(nva.y, bsl); osa.z = f(nva.z, bsl); osa.w = f(nva.w, bsl);
        osb.x = f(nvb.x, bsl); osb.y = f(nvb.y, bsl); osb.z = f(nvb.z, bsl); osb.w = f(nvb.w, bsl);
        oda.x = f(nua.x, bdl); oda.y = f(nua.y, bdl); oda.z = f(nua.z, bdl); oda.w = f(nua.w, bdl);
        odb.x = f(nub.x, bdl); odb.y = f(nub.y, bdl); odb.z = f(nub.z, bdl); odb.w = f(nub.w, bdl);
        float4* os_out = (float4*)(out + (size_t)b * N_NODES) + (size_t)n8 * 2;
        float4* od_out = (float4*)(out + (size_t)(BATCH + b) * N_NODES) + (size_t)n8 * 2;
        os_out[0] = osa; os_out[1] = osb;
        od_out[0] = oda; od_out[1] = odb;
    } else {
        // return_time_pred for batch b: 256 threads, 4 samples each (t = tid*4+i, mask t>1000)
        float bint = p[8], al = p[9], wt = p[10], ps = p[11], ip = p[12];
        int tid = threadIdx.x;
        int lane = tid & 63, wv = tid >> 6;
        float inten[4], c[4];
        float cum = 0.f;
#pragma unroll
        for (int i = 0; i < 4; ++i) {
            int t = tid * 4 + i;
            float x = (bint + al * __expf(-wt * (float)t * 1e-4f)) * ip;
            float v = ps * (__logf(1.0f + __expf(-fabsf(x))) + fmaxf(x, 0.0f));
            if (t > 1000) v = 0.f;
            inten[i] = v;
            cum += 0.01f * v;
            c[i] = cum;
        }
        float tot = cum;
#pragma unroll
        for (int off = 1; off < 64; off <<= 1) {
            float u = __shfl_up(tot, off, 64);
            if (lane >= off) tot += u;
        }
        if (lane == 63) wsum[wv] = tot;
        __syncthreads();
        float wpre = 0.f;
#pragma unroll
        for (int w = 0; w < 4; ++w) if (w < wv) wpre += wsum[w];
        float excl = wpre + tot - cum;   // exclusive prefix for this thread
        float acc = 0.f;
#pragma unroll
        for (int i = 0; i < 4; ++i) {
            int t = tid * 4 + i;
            float integral = excl + c[i];
            float dens = inten[i] * __expf(-integral);
            float w = (t == 0 || t == 1000) ? 0.005f : (t < 1000 ? 0.01f : 0.f);
            acc += w * (float)t * 0.01f * dens;
        }
#pragma unroll
        for (int off = 32; off > 0; off >>= 1) acc += __shfl_down(acc, off, 64);
        if (lane == 0) bred[wv] = acc;
        __syncthreads();
        if (tid == 0)
            out[(size_t)2 * BATCH * N_NODES + b] = bred[0] + bred[1] + bred[2] + bred[3];
    }
}

extern "C" void kernel_launch(void* const* d_in, const int* in_sizes, int n_in,
                              void* d_out, int out_size, void* d_ws, size_t ws_size,
                              hipStream_t stream) {
    const float* emb         = (const float*)d_in[0];
    const int*   assoc       = (const int*)  d_in[1];
    const int*   src         = (const int*)  d_in[2];
    const int*   pdst        = (const int*)  d_in[3];
    const float* last_update = (const float*)d_in[5];
    const float* cur_time    = (const float*)d_in[6];
    const int*   et          = (const int*)  d_in[7];
    const float* W           = (const float*)d_in[8];
    const float* bias        = (const float*)d_in[9];
    const float* psi         = (const float*)d_in[10];
    const float* alpha       = (const float*)d_in[11];
    const float* w_t         = (const float*)d_in[12];
    float* out = (float*)d_out;

    float* ws  = (float*)d_ws;
    float* nv0 = ws;
    float* nv1 = ws + 50000;
    float* nu0 = ws + 100000;
    float* nu1 = ws + 150000;
    float* pb  = ws + 200000;   // 512*16 floats

    prep_kernel<<<198, 256, 0, stream>>>(emb, assoc, src, pdst, last_update, cur_time,
                                         et, W, bias, psi, alpha, w_t,
                                         nv0, nv1, nu0, nu1, pb);
    dim3 grid(26, BATCH);
    main_kernel<<<grid, 256, 0, stream>>>(nv0, nv1, nu0, nu1, pb, out);
}